// Round 10
// baseline (204.011 us; speedup 1.0000x reference)
//
#include <hip/hip_runtime.h>
#include <hip/hip_bf16.h>
#include <stdint.h>

// Problem constants: B=4, S=2048, D=512, H=8, DEPTH=64
#define B_ 4
#define S_ 2048
#define D_ 512
#define H_ 8

typedef __attribute__((ext_vector_type(8))) short short8;
typedef __attribute__((ext_vector_type(4))) short short4v;
typedef __attribute__((ext_vector_type(4))) float f32x4;
typedef __attribute__((ext_vector_type(4))) unsigned short u16x4;

#define MFMA16(a,b,c) __builtin_amdgcn_mfma_f32_16x16x32_bf16((a),(b),(c),0,0,0)
// K=16 bf16 MFMA: A/B-operand k = 4*(lane>>4)+j matches swapped-QK^T C quads.
#define MFMA16K(a,b,c) __builtin_amdgcn_mfma_f32_16x16x16bf16_1k((a),(b),(c),0,0,0)

#if __has_builtin(__builtin_amdgcn_sbfe)
#define SBFE1(v, off) ((uint32_t)__builtin_amdgcn_sbfe((int)(v), (off), 1))
#else
#define SBFE1(v, off) ((uint32_t)(((int32_t)((v) << (31-(off)))) >> 31))
#endif

__device__ __forceinline__ unsigned short f2bf(float f){
    return __builtin_bit_cast(unsigned short, __float2bfloat16(f));
}

__device__ __forceinline__ float maskf(float p, uint32_t keep){
    return __builtin_bit_cast(float, __builtin_bit_cast(uint32_t, p) & keep);
}

__device__ __forceinline__ float max3f(float a, float b, float c){
    float d;
    asm("v_max3_f32 %0, %1, %2, %3" : "=v"(d) : "v"(a), "v"(b), "v"(c));
    return d;
}

__device__ __forceinline__ void gload_lds16(const void* g, void* l){
    __builtin_amdgcn_global_load_lds((const __attribute__((address_space(1))) uint32_t*)g,
                                     (__attribute__((address_space(3))) uint32_t*)l, 16, 0, 0);
}

// ---------------------------------------------------------------------------
// Prep (merged): blocks [0,4096): WT[mat][n][k] = W[mat][k][n] bf16
//                blocks [4096,6144): mask int32 -> bit-pack (bit=1: masked)
// ---------------------------------------------------------------------------
__global__ __launch_bounds__(256) void prep_kernel(
    const int* __restrict__ mask, uint32_t* __restrict__ mout,
    const float* __restrict__ wq, const float* __restrict__ wk,
    const float* __restrict__ wv, const float* __restrict__ wo,
    unsigned short* __restrict__ wt)
{
    int bid = blockIdx.x;
    if (bid < 4096){
        int f = bid*256 + threadIdx.x;                 // 0 .. 4*512*512-1
        int mat = f >> 18;
        int rem = f & 262143;
        const float* Wm = (mat==0)?wq:(mat==1)?wk:(mat==2)?wv:wo;
        int kk = rem >> 9, nn = rem & 511;             // coalesced read of W[k][n]
        wt[(size_t)mat*262144 + (size_t)nn*512 + kk] = f2bf(Wm[rem]);
    } else {
        int idx = (bid-4096)*256 + threadIdx.x;        // 0 .. B*S*64-1
        const int4* p = (const int4*)(mask + (size_t)idx*32);
        uint32_t bits = 0;
        #pragma unroll
        for (int c=0;c<8;c++){
            int4 v = p[c];
            if (v.x) bits |= 1u << (c*4+0);
            if (v.y) bits |= 1u << (c*4+1);
            if (v.z) bits |= 1u << (c*4+2);
            if (v.w) bits |= 1u << (c*4+3);
        }
        mout[idx] = bits;
    }
}

// ---------------------------------------------------------------------------
// Q/K/V projection: X(fp32 [8192][512]) @ W + b.  BK=64 (8 k-steps).
// z=0 (Q): bf16 [B][H][S][64], pre-scaled by 0.125*log2(e) (exp2 domain).
// z=1 (K): bf16 [B][H][S][64].
// z=2 (V): VT[b][n][s'] via swapped MFMA operands. Within each aligned 64-s
//          chunk, kv=16*t4+4*gq+j is stored at e'=32*(t4>>1)+8*gq+4*(t4&1)+j
//          (bijection on [0,64)) so attn PV A-quads are 16B-contiguous.
// ---------------------------------------------------------------------------
__global__ __launch_bounds__(256) void proj_kernel(
    const float* __restrict__ q, const float* __restrict__ k, const float* __restrict__ v,
    const float* __restrict__ bq, const float* __restrict__ bk, const float* __restrict__ bv,
    const unsigned short* __restrict__ wt, unsigned short* __restrict__ outb)
{
    __shared__ uint8_t smem[32768];
    const int t = threadIdx.x, l = t&63, w = t>>6, g = l>>4, ln = l&15;
    const int z = blockIdx.z;
    const float* X = (z==0)? q : (z==1)? k : v;
    const float* bias = (z==0)? bq : (z==1)? bk : bv;
    const unsigned short* WTz = wt + (size_t)z*(D_*D_);
    unsigned short* out = outb + (size_t)z*((size_t)B_*H_*S_*64);
    const float scale = (z==0)? 0.18033688011112042f : 1.0f;  // 0.125*log2(e) for Q
    const int m0 = blockIdx.x*128, n0 = blockIdx.y*128;
    uint8_t* As = smem; uint8_t* Bs = smem + 16384;
    const int RB = (w>>1)*64, CB = (w&1)*64;

    const f32x4 zz = {0.f,0.f,0.f,0.f};
    f32x4 acc[4][4];
    #pragma unroll
    for (int i=0;i<4;i++)
        #pragma unroll
        for (int j=0;j<4;j++) acc[i][j] = zz;

    for (int k0=0; k0<D_; k0+=64){
        __syncthreads();
        // stage WT tile [128 n][64 k] via global_load_lds, pre-swizzled source
        #pragma unroll
        for (int i=0;i<4;i++){
            int qc = w + i*4;                          // 16 chunks of 1KB
            int row = qc*8 + (l>>3);
            int colb = ((l&7)*16) ^ ((row&7)<<4);
            gload_lds16((const uint8_t*)WTz + (((size_t)(n0+row)*D_ + k0)<<1) + colb,
                        Bs + qc*1024);
        }
        // stage X tile [128 m][64 k] fp32->bf16 via cvt_pk, swizzled 16B writes
        #pragma unroll
        for (int i=0;i<4;i++){
            int c = t + i*256;
            int row = c>>3, cc = c&7;
            const float4* src = (const float4*)(X + (size_t)(m0+row)*D_ + k0 + cc*8);
            float4 u0 = src[0], u1 = src[1];
            uint32_t c0,c1,c2,c3;
            asm("v_cvt_pk_bf16_f32 %0, %1, %2" : "=v"(c0) : "v"(u0.x), "v"(u0.y));
            asm("v_cvt_pk_bf16_f32 %0, %1, %2" : "=v"(c1) : "v"(u0.z), "v"(u0.w));
            asm("v_cvt_pk_bf16_f32 %0, %1, %2" : "=v"(c2) : "v"(u1.x), "v"(u1.y));
            asm("v_cvt_pk_bf16_f32 %0, %1, %2" : "=v"(c3) : "v"(u1.z), "v"(u1.w));
            uint4 pk4; pk4.x=c0; pk4.y=c1; pk4.z=c2; pk4.w=c3;
            *(uint4*)(As + row*128 + ((cc*16) ^ ((row&7)<<4))) = pk4;
        }
        __syncthreads();
        #pragma unroll
        for (int kc=0; kc<2; kc++){
            short8 af[4], bfr[4];
            #pragma unroll
            for (int ai=0; ai<4; ai++){
                int row = RB + 16*ai + ln;
                af[ai] = *(const short8*)(As + row*128 + ((16*g + 64*kc) ^ ((row&7)<<4)));
            }
            #pragma unroll
            for (int bj=0; bj<4; bj++){
                int row = CB + 16*bj + ln;
                bfr[bj] = *(const short8*)(Bs + row*128 + ((16*g + 64*kc) ^ ((row&7)<<4)));
            }
            if (z == 2){
                #pragma unroll
                for (int ai=0; ai<4; ai++)
                    #pragma unroll
                    for (int bj=0; bj<4; bj++)
                        acc[ai][bj] = MFMA16(bfr[bj], af[ai], acc[ai][bj]);
            } else {
                #pragma unroll
                for (int ai=0; ai<4; ai++)
                    #pragma unroll
                    for (int bj=0; bj<4; bj++)
                        acc[ai][bj] = MFMA16(af[ai], bfr[bj], acc[ai][bj]);
            }
        }
    }

    if (z == 2){
        // acc[ai][bj]: C row = n (CB+16bj+4g+r), C col = s (RB+16ai+ln).
        // s_local = 16*ai+ln -> t4=ai, gq=ln>>2, j=ln&3;
        // e' = 32*(ai>>1) + 8*(ln>>2) + 4*(ai&1) + (ln&3)
        const int lnperm = 8*(ln>>2) + (ln&3);
        const int bidx = m0 >> 11;                  // whole block in one batch
        const int schunk = (m0 + RB) & 2047;        // 64-aligned
        #pragma unroll
        for (int bj=0; bj<4; bj++){
            #pragma unroll
            for (int ai=0; ai<4; ai++){
                int soff = schunk + 32*(ai>>1) + 4*(ai&1) + lnperm;
                #pragma unroll
                for (int r=0;r<4;r++){
                    int gn = n0 + CB + 16*bj + 4*g + r;
                    float val = acc[ai][bj][r] + bias[gn];
                    out[((size_t)bidx*D_ + gn)*S_ + soff] = f2bf(val);
                }
            }
        }
    } else {
        #pragma unroll
        for (int bj=0; bj<4; bj++){
            int gn = n0 + CB + 16*bj + ln;
            float bv2 = bias[gn];
            int h = gn >> 6, dep = gn & 63;
            #pragma unroll
            for (int ai=0; ai<4; ai++){
                #pragma unroll
                for (int r=0;r<4;r++){
                    int gm = m0 + RB + 16*ai + 4*g + r;
                    float val = (acc[ai][bj][r] + bv2) * scale;
                    size_t o = ((size_t)(gm>>11)*H_ + h)*((size_t)S_*64) + (size_t)(gm&2047)*64 + dep;
                    out[o] = f2bf(val);
                }
            }
        }
    }
}

// ---------------------------------------------------------------------------
// Flash attention v9: V fragments bypass LDS entirely.
//  - K tile: LDS dbuf, 8 conflict-free b128 reads per wave-iter
//  - VT fragments: identical across the block's 4 waves -> read directly
//    from global (pair-permuted layout = one dwordx4 per fragment pair);
//    L1 serves 3 of 4 waves, XCD-pinned L2 serves the rest. Register
//    prefetch (issued right after PV) hides the latency.
//  - P never touches LDS (K=16 PV from registers); XCD-aware remap
// LDS: K dbuf 2x8K only.
// ---------------------------------------------------------------------------
__global__ __launch_bounds__(256, 4) void attn_kernel(
    const unsigned short* __restrict__ qb, const unsigned short* __restrict__ kb,
    const unsigned short* __restrict__ vtb, const uint32_t* __restrict__ mb,
    unsigned short* __restrict__ ao)
{
    __shared__ uint8_t smem[16384];
    const int t = threadIdx.x, l = t&63, w = t>>6, g = l>>4, ln = l&15;
    // XCD-aware remap: fid%8 = XCD (HW round-robin); pin bh group per XCD.
    const int fid = blockIdx.x + 32*blockIdx.y;      // grid (32,32)
    const int slot = fid >> 3;                       // 0..127
    const int bh = (fid & 7) + 8*(slot >> 5);        // 0..31
    const int q0 = (slot & 31) * 64;
    const int b = bh >> 3;
    const unsigned short* Q  = qb + (size_t)bh*((size_t)S_*64);
    const unsigned short* K  = kb + (size_t)bh*((size_t)S_*64);
    const uint8_t* VTb = (const uint8_t*)(vtb + ((size_t)b*D_ + (bh&7)*64)*S_);

    // Q fragments; q row for this lane = q0+16w+ln
    const int qrow = q0 + 16*w + ln;
    const short8 qf0 = *(const short8*)(Q + (size_t)qrow*64 + 8*g);
    const short8 qf1 = *(const short8*)(Q + (size_t)qrow*64 + 8*g + 32);

    // hoisted K LDS read bases (swizzle folded)
    const int Msw = (ln&7)<<4;
    const int sw0 = (16*g) ^ Msw;
    const int sw1 = (16*g + 64) ^ Msw;
    uint8_t* kB0 = smem + ln*128 + sw0;           // K b128 reads: +curb +2048*t4
    uint8_t* kB1 = smem + ln*128 + sw1;

    // K staging: 32-bit per-lane source offsets
    int krow0 = w*8 + (l>>3), krow1 = (w+4)*8 + (l>>3);
    int kof0 = krow0*128 + (((l&7)*16) ^ ((krow0&7)<<4));
    int kof1 = krow1*128 + (((l&7)*16) ^ ((krow1&7)<<4));
    const int ldo0 = w*1024, ldo1 = (w+4)*1024;

    // VT fragment offsets: row d'=16*db+ln, 16B window at byte 16g (+64)
    uint32_t vo0[4], vo1[4];
    uint4 vb0[4], vb1[4];
    #pragma unroll
    for (int db=0; db<4; db++){
        vo0[db] = (uint32_t)(16*db + ln)*(S_*2) + 16*g;
        vo1[db] = vo0[db] + 64;
    }

    const uint2* mptr = (const uint2*)(mb + ((size_t)b*S_ + qrow)*64);

    const f32x4 zz = {0.f,0.f,0.f,0.f};
    f32x4 O[4], O5 = zz;
    #pragma unroll
    for (int i=0;i<4;i++) O[i] = zz;
    float c = 0.f;                      // softmax shift (stays 0 on hot path)

    const short4v onesv = {0x3F80,0x3F80,0x3F80,0x3F80};

    // prologue: stage K tile 0 into buffer 0; load VT frags for tile 0
    gload_lds16((const uint8_t*)K + kof0, smem + ldo0);
    gload_lds16((const uint8_t*)K + kof1, smem + ldo1);
    kof0 += 8192; kof1 += 8192;
    #pragma unroll
    for (int db=0; db<4; db++){
        vb0[db] = *(const uint4*)(VTb + vo0[db]);
        vb1[db] = *(const uint4*)(VTb + vo1[db]);
        vo0[db] += 128; vo1[db] += 128;
    }
    int curb = 0;
    uint2 mmc = mptr[0];

    for (int it=0; it<S_/64; ++it){
        __syncthreads();   // K tile [curb] ready; prior reads of [curb^8192] done
        if (it < S_/64 - 1){
            int nx = curb ^ 8192;
            gload_lds16((const uint8_t*)K + kof0, smem + nx + ldo0);
            gload_lds16((const uint8_t*)K + kof1, smem + nx + ldo1);
            kof0 += 8192; kof1 += 8192;
        }
        uint2 mmn = mptr[(it+1)&31];    // prefetch next mask words
        const uint8_t* b0 = kB0 + curb;
        const uint8_t* b1 = kB1 + curb;

        // ST = K @ Q^T -> lane holds ST[kv=16t4+4g+r][q=ln]
        f32x4 st[4];
        __builtin_amdgcn_s_setprio(1);
        #pragma unroll
        for (int t4=0;t4<4;t4++){
            short8 kf0 = *(const short8*)(b0 + 2048*t4);
            short8 kf1 = *(const short8*)(b1 + 2048*t4);
            st[t4] = MFMA16(kf0, qf0, zz);
            st[t4] = MFMA16(kf1, qf1, st[t4]);
        }
        __builtin_amdgcn_s_setprio(0);

        // overflow guard: per-lane max (no shuffles on hot path)
        float m0a = max3f(st[0][0], st[0][1], st[0][2]);
        float m1a = max3f(st[0][3], st[1][0], st[1][1]);
        float m2a = max3f(st[1][2], st[1][3], st[2][0]);
        float m3a = max3f(st[2][1], st[2][2], st[2][3]);
        float m4a = max3f(st[3][0], st[3][1], st[3][2]);
        float lmax = fmaxf(max3f(m0a, m1a, m2a), max3f(m3a, m4a, st[3][3]));
        if (__builtin_expect(__any(lmax > c + 8.0f), 0)){
            float rm = lmax;
            rm = fmaxf(rm, __shfl_xor(rm, 16));
            rm = fmaxf(rm, __shfl_xor(rm, 32));
            float cnew = fmaxf(c, rm);
            float al = __builtin_amdgcn_exp2f(c - cnew);
            c = cnew;
            #pragma unroll
            for (int r=0;r<4;r++){
                float aO = __shfl(al, 4*g + r);
                #pragma unroll
                for (int db=0; db<4; db++) O[db][r] *= aO;
                O5[r] *= aO;
            }
        }

        // p = exp2(st - c), zero masked, pack to bf16 A-quads
        uint32_t mi0 = (~mmc.x) >> (4*g);
        uint32_t mi1 = (~mmc.y) >> (4*g);
        short4v pa[4];
        auto genp = [&](float cc){
            #pragma unroll
            for (int t4=0;t4<4;t4++){
                uint32_t mi = (t4 >= 2) ? mi1 : mi0;
                const int base = (t4&1)*16;
                float p0 = maskf(__builtin_amdgcn_exp2f(st[t4][0] - cc), SBFE1(mi, base+0));
                float p1 = maskf(__builtin_amdgcn_exp2f(st[t4][1] - cc), SBFE1(mi, base+1));
                float p2 = maskf(__builtin_amdgcn_exp2f(st[t4][2] - cc), SBFE1(mi, base+2));
                float p3 = maskf(__builtin_amdgcn_exp2f(st[t4][3] - cc), SBFE1(mi, base+3));
                uint32_t lo, hi;
                asm("v_cvt_pk_bf16_f32 %0, %1, %2" : "=v"(lo) : "v"(p0), "v"(p1));
                asm("v_cvt_pk_bf16_f32 %0, %1, %2" : "=v"(hi) : "v"(p2), "v"(p3));
                uint2 u; u.x = lo; u.y = hi;
                pa[t4] = __builtin_bit_cast(short4v, u);
            }
        };
        if (__builtin_expect(__all(c == 0.0f), 1)) genp(0.0f); else genp(c);
        mmc = mmn;

        // PV + lsum straight from registers (VT frags already resident)
        __builtin_amdgcn_s_setprio(1);
        #pragma unroll
        for (int db=0; db<4; db++){
            short8 vp0 = __builtin_bit_cast(short8, vb0[db]);
            short8 vp1 = __builtin_bit_cast(short8, vb1[db]);
            short4v vf0 = {vp0[0],vp0[1],vp0[2],vp0[3]};
            short4v vf1 = {vp0[4],vp0[5],vp0[6],vp0[7]};
            short4v vf2 = {vp1[0],vp1[1],vp1[2],vp1[3]};
            short4v vf3 = {vp1[4],vp1[5],vp1[6],vp1[7]};
            O[db] = MFMA16K(pa[0], vf0, O[db]);
            O[db] = MFMA16K(pa[1], vf1, O[db]);
            O[db] = MFMA16K(pa[2], vf2, O[db]);
            O[db] = MFMA16K(pa[3], vf3, O[db]);
        }
        O5 = MFMA16K(pa[0], onesv, O5);
        O5 = MFMA16K(pa[1], onesv, O5);
        O5 = MFMA16K(pa[2], onesv, O5);
        O5 = MFMA16K(pa[3], onesv, O5);
        __builtin_amdgcn_s_setprio(0);

        // prefetch next tile's VT fragments (latency hidden by next QK+softmax)
        if (it < S_/64 - 1){
            #pragma unroll
            for (int db=0; db<4; db++){
                vb0[db] = *(const uint4*)(VTb + vo0[db]);
                vb1[db] = *(const uint4*)(VTb + vo1[db]);
                vo0[db] += 128; vo1[db] += 128;
            }
        }
        curb ^= 8192;
    }

    // normalize and write merged-head bf16 [B*S][512]
    #pragma unroll
    for (int r=0;r<4;r++){
        float inv = 1.0f / O5[r];
        int gm = b*S_ + q0 + 16*w + 4*g + r;
        #pragma unroll
        for (int db=0; db<4; db++){
            int col = (bh&7)*64 + 16*db + ln;
            ao[(size_t)gm*D_ + col] = f2bf(O[db][r]*inv);
        }
    }
}

// ---------------------------------------------------------------------------
// Output projection: ao(bf16 [8192][512]) @ wo + bo -> fp32 out.  BK=64.
// ---------------------------------------------------------------------------
__global__ __launch_bounds__(256) void outproj_kernel(
    const unsigned short* __restrict__ ao, const unsigned short* __restrict__ wt,
    const float* __restrict__ bo, float* __restrict__ out)
{
    __shared__ uint8_t smem[32768];
    const int t = threadIdx.x, l = t&63, w = t>>6, g = l>>4, ln = l&15;
    const unsigned short* WTz = wt + (size_t)3*(D_*D_);
    const int m0 = blockIdx.x*128, n0 = blockIdx.y*128;
    uint8_t* As = smem; uint8_t* Bs = smem + 16384;
    const int RB = (w>>1)*64, CB = (w&1)*64;

    const f32x4 zz = {0.f,0.f,0.f,0.f};
    f32x4 acc[4][4];
    #pragma unroll
    for (int i=0;i<4;i++)
        #pragma unroll
        for (int j=0;j<4;j++) acc[i][j] = zz;

    for (int k0=0; k0<D_; k0+=64){
        __syncthreads();
        #pragma unroll
        for (int i=0;i<4;i++){
            int qc = w + i*4;
            int row = qc*8 + (l>>3);
            int colb = ((l&7)*16) ^ ((row&7)<<4);
            gload_lds16((const uint8_t*)WTz + (((size_t)(n0+row)*D_ + k0)<<1) + colb,
                        Bs + qc*1024);
            gload_lds16((const uint8_t*)ao + (((size_t)(m0+row)*D_ + k0)<<1) + colb,
                        As + qc*1024);
        }
        __syncthreads();
        #pragma unroll
        for (int kc=0; kc<2; kc++){
            short8 af[4], bfr[4];
            #pragma unroll
            for (int ai=0; ai<4; ai++){
                int row = RB + 16*ai + ln;
                af[ai] = *(const short8*)(As + row*128 + ((16*g + 64*kc) ^ ((row&7)<<4)));
            }
            #pragma unroll
            for (int bj=0; bj<4; bj++){
                int row = CB + 16*bj + ln;
                bfr[bj] = *(const short8*)(Bs + row*128 + ((16*g + 64*kc) ^ ((row&7)<<4)));
            }
            #pragma unroll
            for (int ai=0; ai<4; ai++)
                #pragma unroll
                for (int bj=0; bj<4; bj++)
                    acc[ai][bj] = MFMA16(af[ai], bfr[bj], acc[ai][bj]);
        }
    }

    #pragma unroll
    for (int bj=0; bj<4; bj++){
        int gn = n0 + CB + 16*bj + ln;
        float bv2 = bo[gn];
        #pragma unroll
        for (int ai=0; ai<4; ai++){
            #pragma unroll
            for (int r=0;r<4;r++){
                int gm = m0 + RB + 16*ai + 4*g + r;
                out[(size_t)gm*D_ + gn] = acc[ai][bj][r] + bv2;
            }
        }
    }
}

// ---------------------------------------------------------------------------
extern "C" void kernel_launch(void* const* d_in, const int* in_sizes, int n_in,
                              void* d_out, int out_size, void* d_ws, size_t ws_size,
                              hipStream_t stream)
{
    const float* q  = (const float*)d_in[0];
    const float* k  = (const float*)d_in[1];
    const float* v  = (const float*)d_in[2];
    const int* mask = (const int*)d_in[3];
    const float* wq = (const float*)d_in[4];
    const float* bq = (const float*)d_in[5];
    const float* wk = (const float*)d_in[6];
    const float* bk = (const float*)d_in[7];
    const float* wv = (const float*)d_in[8];
    const float* bv = (const float*)d_in[9];
    const float* wo = (const float*)d_in[10];
    const float* bo = (const float*)d_in[11];

    uint8_t* ws = (uint8_t*)d_ws;
    // ws layout (bytes):
    //   0        : qb bf16 [B][H][S][64]            (8388608)
    //   8388608  : kb bf16 [B][H][S][64]            (8388608)
    //   16777216 : vt bf16 [B][512][S] (pair-perm)  (8388608)
    //   25165824 : ao bf16 [8192][512]              (8388608)
    //   33554432 : WT bf16 [4][512][512]            (2097152)
    //   35651584 : mask bits u32 [B*S*64]           (2097152)
    unsigned short* qkvb = (unsigned short*)ws;
    unsigned short* ao   = (unsigned short*)(ws + 25165824);
    unsigned short* wt   = (unsigned short*)(ws + 33554432);
    uint32_t*       mb   = (uint32_t*)      (ws + 35651584);
    float* out = (float*)d_out;

    prep_kernel<<<dim3(6144), dim3(256), 0, stream>>>(mask, mb, wq, wk, wv, wo, wt);
    proj_kernel<<<dim3(64,4,3), dim3(256), 0, stream>>>(q, k, v, bq, bk, bv, wt, qkvb);
    attn_kernel<<<dim3(32,32), dim3(256), 0, stream>>>(qkvb, qkvb + 4194304, qkvb + 8388608, mb, ao);
    outproj_kernel<<<dim3(64,4), dim3(256), 0, stream>>>(ao, wt, bo, out);
}

// Round 11
// 115.615 us; speedup vs baseline: 1.7646x; 1.7646x over previous
//
#include <hip/hip_runtime.h>
#include <hip/hip_bf16.h>
#include <stdint.h>

// Problem constants: B=4, S=2048, D=512, H=8, DEPTH=64
#define B_ 4
#define S_ 2048
#define D_ 512
#define H_ 8

typedef __attribute__((ext_vector_type(8))) short short8;
typedef __attribute__((ext_vector_type(4))) short short4v;
typedef __attribute__((ext_vector_type(4))) float f32x4;
typedef __attribute__((ext_vector_type(4))) unsigned short u16x4;

#define MFMA16(a,b,c) __builtin_amdgcn_mfma_f32_16x16x32_bf16((a),(b),(c),0,0,0)
// K=16 bf16 MFMA: A/B-operand k = 4*(lane>>4)+j matches swapped-QK^T C quads.
#define MFMA16K(a,b,c) __builtin_amdgcn_mfma_f32_16x16x16bf16_1k((a),(b),(c),0,0,0)

#if __has_builtin(__builtin_amdgcn_sbfe)
#define SBFE1(v, off) ((uint32_t)__builtin_amdgcn_sbfe((int)(v), (off), 1))
#else
#define SBFE1(v, off) ((uint32_t)(((int32_t)((v) << (31-(off)))) >> 31))
#endif

__device__ __forceinline__ unsigned short f2bf(float f){
    return __builtin_bit_cast(unsigned short, __float2bfloat16(f));
}

__device__ __forceinline__ float maskf(float p, uint32_t keep){
    return __builtin_bit_cast(float, __builtin_bit_cast(uint32_t, p) & keep);
}

__device__ __forceinline__ float max3f(float a, float b, float c){
    float d;
    asm("v_max3_f32 %0, %1, %2, %3" : "=v"(d) : "v"(a), "v"(b), "v"(c));
    return d;
}

__device__ __forceinline__ void gload_lds16(const void* g, void* l){
    __builtin_amdgcn_global_load_lds((const __attribute__((address_space(1))) uint32_t*)g,
                                     (__attribute__((address_space(3))) uint32_t*)l, 16, 0, 0);
}

// ---------------------------------------------------------------------------
// Prep: WT[mat][n][k] = W[mat][k][n] bf16 (coalesced reads; 2B scattered
// writes at 1KB stride absorbed by L2). Mask-pack lives in proj z=3 now.
// ---------------------------------------------------------------------------
__global__ __launch_bounds__(256) void prep_kernel(
    const float* __restrict__ wq, const float* __restrict__ wk,
    const float* __restrict__ wv, const float* __restrict__ wo,
    unsigned short* __restrict__ wt)
{
    int f = blockIdx.x*256 + threadIdx.x;              // 0 .. 4*512*512-1
    int mat = f >> 18;
    int rem = f & 262143;
    const float* Wm = (mat==0)?wq:(mat==1)?wk:(mat==2)?wv:wo;
    int kk = rem >> 9, nn = rem & 511;                 // coalesced read of W[k][n]
    wt[(size_t)mat*262144 + (size_t)nn*512 + kk] = f2bf(Wm[rem]);
}

// ---------------------------------------------------------------------------
// Q/K/V projection: X(fp32 [8192][512]) @ W + b.  BK=64 (8 k-steps).
// z=0 (Q): bf16 [B][H][S][64], pre-scaled by 0.125*log2(e) (exp2 domain).
// z=1 (K): bf16 [B][H][S][64].
// z=2 (V): VT[b][n][s'] via swapped MFMA operands; kv pair-permutation
//          e'=32*(t4>>1)+8*gq+4*(t4&1)+j within each aligned 64-s chunk.
// z=3 : mask int32 -> bit-pack (memory-bound; overlaps z<3 compute).
// ---------------------------------------------------------------------------
__global__ __launch_bounds__(256) void proj_kernel(
    const float* __restrict__ q, const float* __restrict__ k, const float* __restrict__ v,
    const float* __restrict__ bq, const float* __restrict__ bk, const float* __restrict__ bv,
    const unsigned short* __restrict__ wt, unsigned short* __restrict__ outb,
    const int* __restrict__ mask, uint32_t* __restrict__ mout)
{
    __shared__ uint8_t smem[32768];
    const int t = threadIdx.x, l = t&63, w = t>>6, g = l>>4, ln = l&15;
    const int z = blockIdx.z;

    if (z == 3){
        // mask bit-pack: 256 blocks x 8 segments (grid-stride)
        int seg = blockIdx.x + 64*blockIdx.y;          // 0..255
        #pragma unroll
        for (int i=0;i<8;i++){
            int idx = (seg*8 + i)*256 + t;             // 0 .. B*S*64-1
            const int4* p = (const int4*)(mask + (size_t)idx*32);
            uint32_t bits = 0;
            #pragma unroll
            for (int c=0;c<8;c++){
                int4 vv = p[c];
                if (vv.x) bits |= 1u << (c*4+0);
                if (vv.y) bits |= 1u << (c*4+1);
                if (vv.z) bits |= 1u << (c*4+2);
                if (vv.w) bits |= 1u << (c*4+3);
            }
            mout[idx] = bits;
        }
        return;
    }

    const float* X = (z==0)? q : (z==1)? k : v;
    const float* bias = (z==0)? bq : (z==1)? bk : bv;
    const unsigned short* WTz = wt + (size_t)z*(D_*D_);
    unsigned short* out = outb + (size_t)z*((size_t)B_*H_*S_*64);
    const float scale = (z==0)? 0.18033688011112042f : 1.0f;  // 0.125*log2(e) for Q
    const int m0 = blockIdx.x*128, n0 = blockIdx.y*128;
    uint8_t* As = smem; uint8_t* Bs = smem + 16384;
    const int RB = (w>>1)*64, CB = (w&1)*64;

    const f32x4 zz = {0.f,0.f,0.f,0.f};
    f32x4 acc[4][4];
    #pragma unroll
    for (int i=0;i<4;i++)
        #pragma unroll
        for (int j=0;j<4;j++) acc[i][j] = zz;

    for (int k0=0; k0<D_; k0+=64){
        __syncthreads();
        // stage WT tile [128 n][64 k] via global_load_lds, pre-swizzled source
        #pragma unroll
        for (int i=0;i<4;i++){
            int qc = w + i*4;                          // 16 chunks of 1KB
            int row = qc*8 + (l>>3);
            int colb = ((l&7)*16) ^ ((row&7)<<4);
            gload_lds16((const uint8_t*)WTz + (((size_t)(n0+row)*D_ + k0)<<1) + colb,
                        Bs + qc*1024);
        }
        // stage X tile [128 m][64 k] fp32->bf16 via cvt_pk, swizzled 16B writes
        #pragma unroll
        for (int i=0;i<4;i++){
            int c = t + i*256;
            int row = c>>3, cc = c&7;
            const float4* src = (const float4*)(X + (size_t)(m0+row)*D_ + k0 + cc*8);
            float4 u0 = src[0], u1 = src[1];
            uint32_t c0,c1,c2,c3;
            asm("v_cvt_pk_bf16_f32 %0, %1, %2" : "=v"(c0) : "v"(u0.x), "v"(u0.y));
            asm("v_cvt_pk_bf16_f32 %0, %1, %2" : "=v"(c1) : "v"(u0.z), "v"(u0.w));
            asm("v_cvt_pk_bf16_f32 %0, %1, %2" : "=v"(c2) : "v"(u1.x), "v"(u1.y));
            asm("v_cvt_pk_bf16_f32 %0, %1, %2" : "=v"(c3) : "v"(u1.z), "v"(u1.w));
            uint4 pk4; pk4.x=c0; pk4.y=c1; pk4.z=c2; pk4.w=c3;
            *(uint4*)(As + row*128 + ((cc*16) ^ ((row&7)<<4))) = pk4;
        }
        __syncthreads();
        #pragma unroll
        for (int kc=0; kc<2; kc++){
            short8 af[4], bfr[4];
            #pragma unroll
            for (int ai=0; ai<4; ai++){
                int row = RB + 16*ai + ln;
                af[ai] = *(const short8*)(As + row*128 + ((16*g + 64*kc) ^ ((row&7)<<4)));
            }
            #pragma unroll
            for (int bj=0; bj<4; bj++){
                int row = CB + 16*bj + ln;
                bfr[bj] = *(const short8*)(Bs + row*128 + ((16*g + 64*kc) ^ ((row&7)<<4)));
            }
            if (z == 2){
                #pragma unroll
                for (int ai=0; ai<4; ai++)
                    #pragma unroll
                    for (int bj=0; bj<4; bj++)
                        acc[ai][bj] = MFMA16(bfr[bj], af[ai], acc[ai][bj]);
            } else {
                #pragma unroll
                for (int ai=0; ai<4; ai++)
                    #pragma unroll
                    for (int bj=0; bj<4; bj++)
                        acc[ai][bj] = MFMA16(af[ai], bfr[bj], acc[ai][bj]);
            }
        }
    }

    if (z == 2){
        // acc[ai][bj]: C row = n (CB+16bj+4g+r), C col = s (RB+16ai+ln).
        // s_local = 16*ai+ln -> e' = 32*(ai>>1) + 8*(ln>>2) + 4*(ai&1) + (ln&3)
        const int lnperm = 8*(ln>>2) + (ln&3);
        const int bidx = m0 >> 11;                  // whole block in one batch
        const int schunk = (m0 + RB) & 2047;        // 64-aligned
        #pragma unroll
        for (int bj=0; bj<4; bj++){
            #pragma unroll
            for (int ai=0; ai<4; ai++){
                int soff = schunk + 32*(ai>>1) + 4*(ai&1) + lnperm;
                #pragma unroll
                for (int r=0;r<4;r++){
                    int gn = n0 + CB + 16*bj + 4*g + r;
                    float val = acc[ai][bj][r] + bias[gn];
                    out[((size_t)bidx*D_ + gn)*S_ + soff] = f2bf(val);
                }
            }
        }
    } else {
        #pragma unroll
        for (int bj=0; bj<4; bj++){
            int gn = n0 + CB + 16*bj + ln;
            float bv2 = bias[gn];
            int h = gn >> 6, dep = gn & 63;
            #pragma unroll
            for (int ai=0; ai<4; ai++){
                #pragma unroll
                for (int r=0;r<4;r++){
                    int gm = m0 + RB + 16*ai + 4*g + r;
                    float val = (acc[ai][bj][r] + bv2) * scale;
                    size_t o = ((size_t)(gm>>11)*H_ + h)*((size_t)S_*64) + (size_t)(gm&2047)*64 + dep;
                    out[o] = f2bf(val);
                }
            }
        }
    }
}

// ---------------------------------------------------------------------------
// Flash attention (r9, proven): slot-balanced conflict-free b128 LDS reads.
//  - K tile: 8 b128 per wave-iter; VT tile: pair-permuted kv -> 8 b128
//  - P never touches LDS (K=16 PV from registers); XCD-aware remap
// LDS: K dbuf 2x8K [0,16K), VT dbuf 2x8K [16K,32K).
// ---------------------------------------------------------------------------
__global__ __launch_bounds__(256, 4) void attn_kernel(
    const unsigned short* __restrict__ qb, const unsigned short* __restrict__ kb,
    const unsigned short* __restrict__ vtb, const uint32_t* __restrict__ mb,
    unsigned short* __restrict__ ao)
{
    __shared__ uint8_t smem[32768];
    const int t = threadIdx.x, l = t&63, w = t>>6, g = l>>4, ln = l&15;
    // XCD-aware remap: fid%8 = XCD (HW round-robin); pin bh group per XCD.
    const int fid = blockIdx.x + 32*blockIdx.y;      // grid (32,32)
    const int slot = fid >> 3;                       // 0..127
    const int bh = (fid & 7) + 8*(slot >> 5);        // 0..31
    const int q0 = (slot & 31) * 64;
    const int b = bh >> 3;
    const unsigned short* Q  = qb + (size_t)bh*((size_t)S_*64);
    const unsigned short* K  = kb + (size_t)bh*((size_t)S_*64);
    const unsigned short* VT = vtb + ((size_t)b*D_ + (bh&7)*64)*S_;

    // Q fragments; q row for this lane = q0+16w+ln
    const int qrow = q0 + 16*w + ln;
    const short8 qf0 = *(const short8*)(Q + (size_t)qrow*64 + 8*g);
    const short8 qf1 = *(const short8*)(Q + (size_t)qrow*64 + 8*g + 32);

    // hoisted LDS read bases (swizzle folded)
    const int Msw = (ln&7)<<4;
    const int sw0 = (16*g) ^ Msw;
    const int sw1 = (16*g + 64) ^ Msw;
    uint8_t* kB0 = smem + ln*128 + sw0;           // K b128 reads: +curb +2048*t4
    uint8_t* kB1 = smem + ln*128 + sw1;
    uint8_t* vB  = smem + 16384 + ln*128;         // VT b128 reads (pair layout)
    const int vpo0 = (16*g     ) ^ Msw;           // slot g^(ln&7): t4 pair (0,1)
    const int vpo1 = (16*g + 64) ^ Msw;           // slot (4+g)^(ln&7): pair (2,3)

    // staging: 32-bit per-lane source offsets
    int krow0 = w*8 + (l>>3), krow1 = (w+4)*8 + (l>>3);
    int colb0 = ((l&7)*16) ^ ((krow0&7)<<4);
    int colb1 = ((l&7)*16) ^ ((krow1&7)<<4);
    int kof0 = krow0*128 + colb0,     kof1 = krow1*128 + colb1;
    int vof0 = krow0*(S_*2) + colb0,  vof1 = krow1*(S_*2) + colb1;
    const int ldo0 = w*1024, ldo1 = (w+4)*1024;

    const uint2* mptr = (const uint2*)(mb + ((size_t)b*S_ + qrow)*64);

    const f32x4 zz = {0.f,0.f,0.f,0.f};
    f32x4 O[4], O5 = zz;
    #pragma unroll
    for (int i=0;i<4;i++) O[i] = zz;
    float c = 0.f;                      // softmax shift (stays 0 on hot path)

    const short4v onesv = {0x3F80,0x3F80,0x3F80,0x3F80};

    // prologue: stage tile 0 into buffer 0
    gload_lds16((const uint8_t*)K  + kof0, smem + ldo0);
    gload_lds16((const uint8_t*)K  + kof1, smem + ldo1);
    gload_lds16((const uint8_t*)VT + vof0, smem + 16384 + ldo0);
    gload_lds16((const uint8_t*)VT + vof1, smem + 16384 + ldo1);
    kof0 += 8192; kof1 += 8192; vof0 += 128; vof1 += 128;
    int curb = 0;
    uint2 mmc = mptr[0];

    for (int it=0; it<S_/64; ++it){
        __syncthreads();   // staged tile [curb] ready; prior reads of [curb^8192] done
        if (it < S_/64 - 1){
            int nx = curb ^ 8192;
            gload_lds16((const uint8_t*)K  + kof0, smem + nx + ldo0);
            gload_lds16((const uint8_t*)K  + kof1, smem + nx + ldo1);
            gload_lds16((const uint8_t*)VT + vof0, smem + 16384 + nx + ldo0);
            gload_lds16((const uint8_t*)VT + vof1, smem + 16384 + nx + ldo1);
            kof0 += 8192; kof1 += 8192; vof0 += 128; vof1 += 128;
        }
        uint2 mmn = mptr[(it+1)&31];    // prefetch next mask words
        const uint8_t* b0 = kB0 + curb;
        const uint8_t* b1 = kB1 + curb;

        // ST = K @ Q^T -> lane holds ST[kv=16t4+4g+r][q=ln]
        f32x4 st[4];
        __builtin_amdgcn_s_setprio(1);
        #pragma unroll
        for (int t4=0;t4<4;t4++){
            short8 kf0 = *(const short8*)(b0 + 2048*t4);
            short8 kf1 = *(const short8*)(b1 + 2048*t4);
            st[t4] = MFMA16(kf0, qf0, zz);
            st[t4] = MFMA16(kf1, qf1, st[t4]);
        }
        __builtin_amdgcn_s_setprio(0);

        // overflow guard: per-lane max (no shuffles on hot path)
        float m0a = max3f(st[0][0], st[0][1], st[0][2]);
        float m1a = max3f(st[0][3], st[1][0], st[1][1]);
        float m2a = max3f(st[1][2], st[1][3], st[2][0]);
        float m3a = max3f(st[2][1], st[2][2], st[2][3]);
        float m4a = max3f(st[3][0], st[3][1], st[3][2]);
        float lmax = fmaxf(max3f(m0a, m1a, m2a), max3f(m3a, m4a, st[3][3]));
        if (__builtin_expect(__any(lmax > c + 8.0f), 0)){
            float rm = lmax;
            rm = fmaxf(rm, __shfl_xor(rm, 16));
            rm = fmaxf(rm, __shfl_xor(rm, 32));
            float cnew = fmaxf(c, rm);
            float al = __builtin_amdgcn_exp2f(c - cnew);
            c = cnew;
            #pragma unroll
            for (int r=0;r<4;r++){
                float aO = __shfl(al, 4*g + r);
                #pragma unroll
                for (int db=0; db<4; db++) O[db][r] *= aO;
                O5[r] *= aO;
            }
        }

        // p = exp2(st - c), zero masked, pack to bf16 A-quads
        uint32_t mi0 = (~mmc.x) >> (4*g);
        uint32_t mi1 = (~mmc.y) >> (4*g);
        short4v pa[4];
        auto genp = [&](float cc){
            #pragma unroll
            for (int t4=0;t4<4;t4++){
                uint32_t mi = (t4 >= 2) ? mi1 : mi0;
                const int base = (t4&1)*16;
                float p0 = maskf(__builtin_amdgcn_exp2f(st[t4][0] - cc), SBFE1(mi, base+0));
                float p1 = maskf(__builtin_amdgcn_exp2f(st[t4][1] - cc), SBFE1(mi, base+1));
                float p2 = maskf(__builtin_amdgcn_exp2f(st[t4][2] - cc), SBFE1(mi, base+2));
                float p3 = maskf(__builtin_amdgcn_exp2f(st[t4][3] - cc), SBFE1(mi, base+3));
                uint32_t lo, hi;
                asm("v_cvt_pk_bf16_f32 %0, %1, %2" : "=v"(lo) : "v"(p0), "v"(p1));
                asm("v_cvt_pk_bf16_f32 %0, %1, %2" : "=v"(hi) : "v"(p2), "v"(p3));
                uint2 u; u.x = lo; u.y = hi;
                pa[t4] = __builtin_bit_cast(short4v, u);
            }
        };
        if (__builtin_expect(__all(c == 0.0f), 1)) genp(0.0f); else genp(c);
        mmc = mmn;

        // PV + lsum straight from registers; VT via b128 pair reads
        __builtin_amdgcn_s_setprio(1);
        const uint8_t* vb = vB + curb;
        #pragma unroll
        for (int db=0; db<4; db++){
            short8 vp0 = *(const short8*)(vb + 2048*db + vpo0);
            short8 vp1 = *(const short8*)(vb + 2048*db + vpo1);
            short4v vf0 = {vp0[0],vp0[1],vp0[2],vp0[3]};
            short4v vf1 = {vp0[4],vp0[5],vp0[6],vp0[7]};
            short4v vf2 = {vp1[0],vp1[1],vp1[2],vp1[3]};
            short4v vf3 = {vp1[4],vp1[5],vp1[6],vp1[7]};
            O[db] = MFMA16K(pa[0], vf0, O[db]);
            O[db] = MFMA16K(pa[1], vf1, O[db]);
            O[db] = MFMA16K(pa[2], vf2, O[db]);
            O[db] = MFMA16K(pa[3], vf3, O[db]);
        }
        O5 = MFMA16K(pa[0], onesv, O5);
        O5 = MFMA16K(pa[1], onesv, O5);
        O5 = MFMA16K(pa[2], onesv, O5);
        O5 = MFMA16K(pa[3], onesv, O5);
        __builtin_amdgcn_s_setprio(0);
        curb ^= 8192;
    }

    // normalize and write merged-head bf16 [B*S][512]
    #pragma unroll
    for (int r=0;r<4;r++){
        float inv = 1.0f / O5[r];
        int gm = b*S_ + q0 + 16*w + 4*g + r;
        #pragma unroll
        for (int db=0; db<4; db++){
            int col = (bh&7)*64 + 16*db + ln;
            ao[(size_t)gm*D_ + col] = f2bf(O[db][r]*inv);
        }
    }
}

// ---------------------------------------------------------------------------
// Output projection: ao(bf16 [8192][512]) @ wo + bo -> fp32 out.  BK=64.
// ---------------------------------------------------------------------------
__global__ __launch_bounds__(256) void outproj_kernel(
    const unsigned short* __restrict__ ao, const unsigned short* __restrict__ wt,
    const float* __restrict__ bo, float* __restrict__ out)
{
    __shared__ uint8_t smem[32768];
    const int t = threadIdx.x, l = t&63, w = t>>6, g = l>>4, ln = l&15;
    const unsigned short* WTz = wt + (size_t)3*(D_*D_);
    const int m0 = blockIdx.x*128, n0 = blockIdx.y*128;
    uint8_t* As = smem; uint8_t* Bs = smem + 16384;
    const int RB = (w>>1)*64, CB = (w&1)*64;

    const f32x4 zz = {0.f,0.f,0.f,0.f};
    f32x4 acc[4][4];
    #pragma unroll
    for (int i=0;i<4;i++)
        #pragma unroll
        for (int j=0;j<4;j++) acc[i][j] = zz;

    for (int k0=0; k0<D_; k0+=64){
        __syncthreads();
        #pragma unroll
        for (int i=0;i<4;i++){
            int qc = w + i*4;
            int row = qc*8 + (l>>3);
            int colb = ((l&7)*16) ^ ((row&7)<<4);
            gload_lds16((const uint8_t*)WTz + (((size_t)(n0+row)*D_ + k0)<<1) + colb,
                        Bs + qc*1024);
            gload_lds16((const uint8_t*)ao + (((size_t)(m0+row)*D_ + k0)<<1) + colb,
                        As + qc*1024);
        }
        __syncthreads();
        #pragma unroll
        for (int kc=0; kc<2; kc++){
            short8 af[4], bfr[4];
            #pragma unroll
            for (int ai=0; ai<4; ai++){
                int row = RB + 16*ai + ln;
                af[ai] = *(const short8*)(As + row*128 + ((16*g + 64*kc) ^ ((row&7)<<4)));
            }
            #pragma unroll
            for (int bj=0; bj<4; bj++){
                int row = CB + 16*bj + ln;
                bfr[bj] = *(const short8*)(Bs + row*128 + ((16*g + 64*kc) ^ ((row&7)<<4)));
            }
            #pragma unroll
            for (int ai=0; ai<4; ai++)
                #pragma unroll
                for (int bj=0; bj<4; bj++)
                    acc[ai][bj] = MFMA16(af[ai], bfr[bj], acc[ai][bj]);
        }
    }

    #pragma unroll
    for (int bj=0; bj<4; bj++){
        int gn = n0 + CB + 16*bj + ln;
        float bv2 = bo[gn];
        #pragma unroll
        for (int ai=0; ai<4; ai++){
            #pragma unroll
            for (int r=0;r<4;r++){
                int gm = m0 + RB + 16*ai + 4*g + r;
                out[(size_t)gm*D_ + gn] = acc[ai][bj][r] + bv2;
            }
        }
    }
}

// ---------------------------------------------------------------------------
extern "C" void kernel_launch(void* const* d_in, const int* in_sizes, int n_in,
                              void* d_out, int out_size, void* d_ws, size_t ws_size,
                              hipStream_t stream)
{
    const float* q  = (const float*)d_in[0];
    const float* k  = (const float*)d_in[1];
    const float* v  = (const float*)d_in[2];
    const int* mask = (const int*)d_in[3];
    const float* wq = (const float*)d_in[4];
    const float* bq = (const float*)d_in[5];
    const float* wk = (const float*)d_in[6];
    const float* bk = (const float*)d_in[7];
    const float* wv = (const float*)d_in[8];
    const float* bv = (const float*)d_in[9];
    const float* wo = (const float*)d_in[10];
    const float* bo = (const float*)d_in[11];

    uint8_t* ws = (uint8_t*)d_ws;
    // ws layout (bytes):
    //   0        : qb bf16 [B][H][S][64]            (8388608)
    //   8388608  : kb bf16 [B][H][S][64]            (8388608)
    //   16777216 : vt bf16 [B][512][S] (pair-perm)  (8388608)
    //   25165824 : ao bf16 [8192][512]              (8388608)
    //   33554432 : WT bf16 [4][512][512]            (2097152)
    //   35651584 : mask bits u32 [B*S*64]           (2097152)
    unsigned short* qkvb = (unsigned short*)ws;
    unsigned short* ao   = (unsigned short*)(ws + 25165824);
    unsigned short* wt   = (unsigned short*)(ws + 33554432);
    uint32_t*       mb   = (uint32_t*)      (ws + 35651584);
    float* out = (float*)d_out;

    prep_kernel<<<dim3(4096), dim3(256), 0, stream>>>(wq, wk, wv, wo, wt);
    proj_kernel<<<dim3(64,4,4), dim3(256), 0, stream>>>(q, k, v, bq, bk, bv, wt, qkvb, mask, mb);
    attn_kernel<<<dim3(32,32), dim3(256), 0, stream>>>(qkvb, qkvb + 4194304, qkvb + 8388608, mb, ao);
    outproj_kernel<<<dim3(64,4), dim3(256), 0, stream>>>(ao, wt, bo, out);
}

// Round 12
// 114.134 us; speedup vs baseline: 1.7875x; 1.0130x over previous
//
#include <hip/hip_runtime.h>
#include <hip/hip_bf16.h>
#include <stdint.h>

// Problem constants: B=4, S=2048, D=512, H=8, DEPTH=64
#define B_ 4
#define S_ 2048
#define D_ 512
#define H_ 8

typedef __attribute__((ext_vector_type(8))) short short8;
typedef __attribute__((ext_vector_type(4))) short short4v;
typedef __attribute__((ext_vector_type(4))) float f32x4;
typedef __attribute__((ext_vector_type(4))) unsigned short u16x4;

#define MFMA16(a,b,c) __builtin_amdgcn_mfma_f32_16x16x32_bf16((a),(b),(c),0,0,0)
// K=16 bf16 MFMA: A/B-operand k = 4*(lane>>4)+j matches swapped-QK^T C quads.
#define MFMA16K(a,b,c) __builtin_amdgcn_mfma_f32_16x16x16bf16_1k((a),(b),(c),0,0,0)

#if __has_builtin(__builtin_amdgcn_sbfe)
#define SBFE1(v, off) ((uint32_t)__builtin_amdgcn_sbfe((int)(v), (off), 1))
#else
#define SBFE1(v, off) ((uint32_t)(((int32_t)((v) << (31-(off)))) >> 31))
#endif

__device__ __forceinline__ unsigned short f2bf(float f){
    return __builtin_bit_cast(unsigned short, __float2bfloat16(f));
}

__device__ __forceinline__ float maskf(float p, uint32_t keep){
    return __builtin_bit_cast(float, __builtin_bit_cast(uint32_t, p) & keep);
}

__device__ __forceinline__ float max3f(float a, float b, float c){
    float d;
    asm("v_max3_f32 %0, %1, %2, %3" : "=v"(d) : "v"(a), "v"(b), "v"(c));
    return d;
}

__device__ __forceinline__ void gload_lds16(const void* g, void* l){
    __builtin_amdgcn_global_load_lds((const __attribute__((address_space(1))) uint32_t*)g,
                                     (__attribute__((address_space(3))) uint32_t*)l, 16, 0, 0);
}

// ---------------------------------------------------------------------------
// Prep: WT[mat][n][k] = W[mat][k][n] bf16 (coalesced reads; 2B scattered
// writes at 1KB stride absorbed by L2). Mask-pack lives in proj z>=3.
// ---------------------------------------------------------------------------
__global__ __launch_bounds__(256) void prep_kernel(
    const float* __restrict__ wq, const float* __restrict__ wk,
    const float* __restrict__ wv, const float* __restrict__ wo,
    unsigned short* __restrict__ wt)
{
    int f = blockIdx.x*256 + threadIdx.x;              // 0 .. 4*512*512-1
    int mat = f >> 18;
    int rem = f & 262143;
    const float* Wm = (mat==0)?wq:(mat==1)?wk:(mat==2)?wv:wo;
    int kk = rem >> 9, nn = rem & 511;                 // coalesced read of W[k][n]
    wt[(size_t)mat*262144 + (size_t)nn*512 + kk] = f2bf(Wm[rem]);
}

// ---------------------------------------------------------------------------
// Q/K/V projection: X(fp32 [8192][512]) @ W + b.  BK=64 (8 k-steps).
// z=0 (Q): bf16 [B][H][S][64], pre-scaled by 0.125*log2(e) (exp2 domain).
// z=1 (K): bf16 [B][H][S][64].
// z=2 (V): VT[b][n][s'] via swapped MFMA operands; kv pair-permutation
//          e'=32*(t4>>1)+8*gq+4*(t4&1)+j within each aligned 64-s chunk.
// z=3..10: mask int32 -> bit-pack, 8 planes x 256 blocks = 2048 blocks
//          (1 idx per thread; memory-bound, overlaps z<3 GEMM compute).
// ---------------------------------------------------------------------------
__global__ __launch_bounds__(256) void proj_kernel(
    const float* __restrict__ q, const float* __restrict__ k, const float* __restrict__ v,
    const float* __restrict__ bq, const float* __restrict__ bk, const float* __restrict__ bv,
    const unsigned short* __restrict__ wt, unsigned short* __restrict__ outb,
    const int* __restrict__ mask, uint32_t* __restrict__ mout)
{
    __shared__ uint8_t smem[32768];
    const int t = threadIdx.x, l = t&63, w = t>>6, g = l>>4, ln = l&15;
    const int z = blockIdx.z;

    if (z >= 3){
        // mask bit-pack: seg = plane*256 + (y*64+x), one u32 word per thread
        int seg = (z-3)*256 + blockIdx.y*64 + blockIdx.x;   // 0..2047
        int idx = seg*256 + t;                              // 0 .. B*S*64-1
        const int4* p = (const int4*)(mask + (size_t)idx*32);
        uint32_t bits = 0;
        #pragma unroll
        for (int c=0;c<8;c++){
            int4 vv = p[c];
            if (vv.x) bits |= 1u << (c*4+0);
            if (vv.y) bits |= 1u << (c*4+1);
            if (vv.z) bits |= 1u << (c*4+2);
            if (vv.w) bits |= 1u << (c*4+3);
        }
        mout[idx] = bits;
        return;
    }

    const float* X = (z==0)? q : (z==1)? k : v;
    const float* bias = (z==0)? bq : (z==1)? bk : bv;
    const unsigned short* WTz = wt + (size_t)z*(D_*D_);
    unsigned short* out = outb + (size_t)z*((size_t)B_*H_*S_*64);
    const float scale = (z==0)? 0.18033688011112042f : 1.0f;  // 0.125*log2(e) for Q
    const int m0 = blockIdx.x*128, n0 = blockIdx.y*128;
    uint8_t* As = smem; uint8_t* Bs = smem + 16384;
    const int RB = (w>>1)*64, CB = (w&1)*64;

    const f32x4 zz = {0.f,0.f,0.f,0.f};
    f32x4 acc[4][4];
    #pragma unroll
    for (int i=0;i<4;i++)
        #pragma unroll
        for (int j=0;j<4;j++) acc[i][j] = zz;

    for (int k0=0; k0<D_; k0+=64){
        __syncthreads();
        // stage WT tile [128 n][64 k] via global_load_lds, pre-swizzled source
        #pragma unroll
        for (int i=0;i<4;i++){
            int qc = w + i*4;                          // 16 chunks of 1KB
            int row = qc*8 + (l>>3);
            int colb = ((l&7)*16) ^ ((row&7)<<4);
            gload_lds16((const uint8_t*)WTz + (((size_t)(n0+row)*D_ + k0)<<1) + colb,
                        Bs + qc*1024);
        }
        // stage X tile [128 m][64 k] fp32->bf16 via cvt_pk, swizzled 16B writes
        #pragma unroll
        for (int i=0;i<4;i++){
            int c = t + i*256;
            int row = c>>3, cc = c&7;
            const float4* src = (const float4*)(X + (size_t)(m0+row)*D_ + k0 + cc*8);
            float4 u0 = src[0], u1 = src[1];
            uint32_t c0,c1,c2,c3;
            asm("v_cvt_pk_bf16_f32 %0, %1, %2" : "=v"(c0) : "v"(u0.x), "v"(u0.y));
            asm("v_cvt_pk_bf16_f32 %0, %1, %2" : "=v"(c1) : "v"(u0.z), "v"(u0.w));
            asm("v_cvt_pk_bf16_f32 %0, %1, %2" : "=v"(c2) : "v"(u1.x), "v"(u1.y));
            asm("v_cvt_pk_bf16_f32 %0, %1, %2" : "=v"(c3) : "v"(u1.z), "v"(u1.w));
            uint4 pk4; pk4.x=c0; pk4.y=c1; pk4.z=c2; pk4.w=c3;
            *(uint4*)(As + row*128 + ((cc*16) ^ ((row&7)<<4))) = pk4;
        }
        __syncthreads();
        #pragma unroll
        for (int kc=0; kc<2; kc++){
            short8 af[4], bfr[4];
            #pragma unroll
            for (int ai=0; ai<4; ai++){
                int row = RB + 16*ai + ln;
                af[ai] = *(const short8*)(As + row*128 + ((16*g + 64*kc) ^ ((row&7)<<4)));
            }
            #pragma unroll
            for (int bj=0; bj<4; bj++){
                int row = CB + 16*bj + ln;
                bfr[bj] = *(const short8*)(Bs + row*128 + ((16*g + 64*kc) ^ ((row&7)<<4)));
            }
            if (z == 2){
                #pragma unroll
                for (int ai=0; ai<4; ai++)
                    #pragma unroll
                    for (int bj=0; bj<4; bj++)
                        acc[ai][bj] = MFMA16(bfr[bj], af[ai], acc[ai][bj]);
            } else {
                #pragma unroll
                for (int ai=0; ai<4; ai++)
                    #pragma unroll
                    for (int bj=0; bj<4; bj++)
                        acc[ai][bj] = MFMA16(af[ai], bfr[bj], acc[ai][bj]);
            }
        }
    }

    if (z == 2){
        // acc[ai][bj]: C row = n (CB+16bj+4g+r), C col = s (RB+16ai+ln).
        // s_local = 16*ai+ln -> e' = 32*(ai>>1) + 8*(ln>>2) + 4*(ai&1) + (ln&3)
        const int lnperm = 8*(ln>>2) + (ln&3);
        const int bidx = m0 >> 11;                  // whole block in one batch
        const int schunk = (m0 + RB) & 2047;        // 64-aligned
        #pragma unroll
        for (int bj=0; bj<4; bj++){
            #pragma unroll
            for (int ai=0; ai<4; ai++){
                int soff = schunk + 32*(ai>>1) + 4*(ai&1) + lnperm;
                #pragma unroll
                for (int r=0;r<4;r++){
                    int gn = n0 + CB + 16*bj + 4*g + r;
                    float val = acc[ai][bj][r] + bias[gn];
                    out[((size_t)bidx*D_ + gn)*S_ + soff] = f2bf(val);
                }
            }
        }
    } else {
        #pragma unroll
        for (int bj=0; bj<4; bj++){
            int gn = n0 + CB + 16*bj + ln;
            float bv2 = bias[gn];
            int h = gn >> 6, dep = gn & 63;
            #pragma unroll
            for (int ai=0; ai<4; ai++){
                #pragma unroll
                for (int r=0;r<4;r++){
                    int gm = m0 + RB + 16*ai + 4*g + r;
                    float val = (acc[ai][bj][r] + bv2) * scale;
                    size_t o = ((size_t)(gm>>11)*H_ + h)*((size_t)S_*64) + (size_t)(gm&2047)*64 + dep;
                    out[o] = f2bf(val);
                }
            }
        }
    }
}

// ---------------------------------------------------------------------------
// Flash attention (r9, proven): slot-balanced conflict-free b128 LDS reads.
//  - K tile: 8 b128 per wave-iter; VT tile: pair-permuted kv -> 8 b128
//  - P never touches LDS (K=16 PV from registers); XCD-aware remap
// LDS: K dbuf 2x8K [0,16K), VT dbuf 2x8K [16K,32K).
// ---------------------------------------------------------------------------
__global__ __launch_bounds__(256, 4) void attn_kernel(
    const unsigned short* __restrict__ qb, const unsigned short* __restrict__ kb,
    const unsigned short* __restrict__ vtb, const uint32_t* __restrict__ mb,
    unsigned short* __restrict__ ao)
{
    __shared__ uint8_t smem[32768];
    const int t = threadIdx.x, l = t&63, w = t>>6, g = l>>4, ln = l&15;
    // XCD-aware remap: fid%8 = XCD (HW round-robin); pin bh group per XCD.
    const int fid = blockIdx.x + 32*blockIdx.y;      // grid (32,32)
    const int slot = fid >> 3;                       // 0..127
    const int bh = (fid & 7) + 8*(slot >> 5);        // 0..31
    const int q0 = (slot & 31) * 64;
    const int b = bh >> 3;
    const unsigned short* Q  = qb + (size_t)bh*((size_t)S_*64);
    const unsigned short* K  = kb + (size_t)bh*((size_t)S_*64);
    const unsigned short* VT = vtb + ((size_t)b*D_ + (bh&7)*64)*S_;

    // Q fragments; q row for this lane = q0+16w+ln
    const int qrow = q0 + 16*w + ln;
    const short8 qf0 = *(const short8*)(Q + (size_t)qrow*64 + 8*g);
    const short8 qf1 = *(const short8*)(Q + (size_t)qrow*64 + 8*g + 32);

    // hoisted LDS read bases (swizzle folded)
    const int Msw = (ln&7)<<4;
    const int sw0 = (16*g) ^ Msw;
    const int sw1 = (16*g + 64) ^ Msw;
    uint8_t* kB0 = smem + ln*128 + sw0;           // K b128 reads: +curb +2048*t4
    uint8_t* kB1 = smem + ln*128 + sw1;
    uint8_t* vB  = smem + 16384 + ln*128;         // VT b128 reads (pair layout)
    const int vpo0 = (16*g     ) ^ Msw;           // slot g^(ln&7): t4 pair (0,1)
    const int vpo1 = (16*g + 64) ^ Msw;           // slot (4+g)^(ln&7): pair (2,3)

    // staging: 32-bit per-lane source offsets
    int krow0 = w*8 + (l>>3), krow1 = (w+4)*8 + (l>>3);
    int colb0 = ((l&7)*16) ^ ((krow0&7)<<4);
    int colb1 = ((l&7)*16) ^ ((krow1&7)<<4);
    int kof0 = krow0*128 + colb0,     kof1 = krow1*128 + colb1;
    int vof0 = krow0*(S_*2) + colb0,  vof1 = krow1*(S_*2) + colb1;
    const int ldo0 = w*1024, ldo1 = (w+4)*1024;

    const uint2* mptr = (const uint2*)(mb + ((size_t)b*S_ + qrow)*64);

    const f32x4 zz = {0.f,0.f,0.f,0.f};
    f32x4 O[4], O5 = zz;
    #pragma unroll
    for (int i=0;i<4;i++) O[i] = zz;
    float c = 0.f;                      // softmax shift (stays 0 on hot path)

    const short4v onesv = {0x3F80,0x3F80,0x3F80,0x3F80};

    // prologue: stage tile 0 into buffer 0
    gload_lds16((const uint8_t*)K  + kof0, smem + ldo0);
    gload_lds16((const uint8_t*)K  + kof1, smem + ldo1);
    gload_lds16((const uint8_t*)VT + vof0, smem + 16384 + ldo0);
    gload_lds16((const uint8_t*)VT + vof1, smem + 16384 + ldo1);
    kof0 += 8192; kof1 += 8192; vof0 += 128; vof1 += 128;
    int curb = 0;
    uint2 mmc = mptr[0];

    for (int it=0; it<S_/64; ++it){
        __syncthreads();   // staged tile [curb] ready; prior reads of [curb^8192] done
        if (it < S_/64 - 1){
            int nx = curb ^ 8192;
            gload_lds16((const uint8_t*)K  + kof0, smem + nx + ldo0);
            gload_lds16((const uint8_t*)K  + kof1, smem + nx + ldo1);
            gload_lds16((const uint8_t*)VT + vof0, smem + 16384 + nx + ldo0);
            gload_lds16((const uint8_t*)VT + vof1, smem + 16384 + nx + ldo1);
            kof0 += 8192; kof1 += 8192; vof0 += 128; vof1 += 128;
        }
        uint2 mmn = mptr[(it+1)&31];    // prefetch next mask words
        const uint8_t* b0 = kB0 + curb;
        const uint8_t* b1 = kB1 + curb;

        // ST = K @ Q^T -> lane holds ST[kv=16t4+4g+r][q=ln]
        f32x4 st[4];
        __builtin_amdgcn_s_setprio(1);
        #pragma unroll
        for (int t4=0;t4<4;t4++){
            short8 kf0 = *(const short8*)(b0 + 2048*t4);
            short8 kf1 = *(const short8*)(b1 + 2048*t4);
            st[t4] = MFMA16(kf0, qf0, zz);
            st[t4] = MFMA16(kf1, qf1, st[t4]);
        }
        __builtin_amdgcn_s_setprio(0);

        // overflow guard: per-lane max (no shuffles on hot path)
        float m0a = max3f(st[0][0], st[0][1], st[0][2]);
        float m1a = max3f(st[0][3], st[1][0], st[1][1]);
        float m2a = max3f(st[1][2], st[1][3], st[2][0]);
        float m3a = max3f(st[2][1], st[2][2], st[2][3]);
        float m4a = max3f(st[3][0], st[3][1], st[3][2]);
        float lmax = fmaxf(max3f(m0a, m1a, m2a), max3f(m3a, m4a, st[3][3]));
        if (__builtin_expect(__any(lmax > c + 8.0f), 0)){
            float rm = lmax;
            rm = fmaxf(rm, __shfl_xor(rm, 16));
            rm = fmaxf(rm, __shfl_xor(rm, 32));
            float cnew = fmaxf(c, rm);
            float al = __builtin_amdgcn_exp2f(c - cnew);
            c = cnew;
            #pragma unroll
            for (int r=0;r<4;r++){
                float aO = __shfl(al, 4*g + r);
                #pragma unroll
                for (int db=0; db<4; db++) O[db][r] *= aO;
                O5[r] *= aO;
            }
        }

        // p = exp2(st - c), zero masked, pack to bf16 A-quads
        uint32_t mi0 = (~mmc.x) >> (4*g);
        uint32_t mi1 = (~mmc.y) >> (4*g);
        short4v pa[4];
        auto genp = [&](float cc){
            #pragma unroll
            for (int t4=0;t4<4;t4++){
                uint32_t mi = (t4 >= 2) ? mi1 : mi0;
                const int base = (t4&1)*16;
                float p0 = maskf(__builtin_amdgcn_exp2f(st[t4][0] - cc), SBFE1(mi, base+0));
                float p1 = maskf(__builtin_amdgcn_exp2f(st[t4][1] - cc), SBFE1(mi, base+1));
                float p2 = maskf(__builtin_amdgcn_exp2f(st[t4][2] - cc), SBFE1(mi, base+2));
                float p3 = maskf(__builtin_amdgcn_exp2f(st[t4][3] - cc), SBFE1(mi, base+3));
                uint32_t lo, hi;
                asm("v_cvt_pk_bf16_f32 %0, %1, %2" : "=v"(lo) : "v"(p0), "v"(p1));
                asm("v_cvt_pk_bf16_f32 %0, %1, %2" : "=v"(hi) : "v"(p2), "v"(p3));
                uint2 u; u.x = lo; u.y = hi;
                pa[t4] = __builtin_bit_cast(short4v, u);
            }
        };
        if (__builtin_expect(__all(c == 0.0f), 1)) genp(0.0f); else genp(c);
        mmc = mmn;

        // PV + lsum straight from registers; VT via b128 pair reads
        __builtin_amdgcn_s_setprio(1);
        const uint8_t* vb = vB + curb;
        #pragma unroll
        for (int db=0; db<4; db++){
            short8 vp0 = *(const short8*)(vb + 2048*db + vpo0);
            short8 vp1 = *(const short8*)(vb + 2048*db + vpo1);
            short4v vf0 = {vp0[0],vp0[1],vp0[2],vp0[3]};
            short4v vf1 = {vp0[4],vp0[5],vp0[6],vp0[7]};
            short4v vf2 = {vp1[0],vp1[1],vp1[2],vp1[3]};
            short4v vf3 = {vp1[4],vp1[5],vp1[6],vp1[7]};
            O[db] = MFMA16K(pa[0], vf0, O[db]);
            O[db] = MFMA16K(pa[1], vf1, O[db]);
            O[db] = MFMA16K(pa[2], vf2, O[db]);
            O[db] = MFMA16K(pa[3], vf3, O[db]);
        }
        O5 = MFMA16K(pa[0], onesv, O5);
        O5 = MFMA16K(pa[1], onesv, O5);
        O5 = MFMA16K(pa[2], onesv, O5);
        O5 = MFMA16K(pa[3], onesv, O5);
        __builtin_amdgcn_s_setprio(0);
        curb ^= 8192;
    }

    // normalize and write merged-head bf16 [B*S][512]
    #pragma unroll
    for (int r=0;r<4;r++){
        float inv = 1.0f / O5[r];
        int gm = b*S_ + q0 + 16*w + 4*g + r;
        #pragma unroll
        for (int db=0; db<4; db++){
            int col = (bh&7)*64 + 16*db + ln;
            ao[(size_t)gm*D_ + col] = f2bf(O[db][r]*inv);
        }
    }
}

// ---------------------------------------------------------------------------
// Output projection: ao(bf16 [8192][512]) @ wo + bo -> fp32 out.
// BK=64, tile 128x64 (grid 64x8 = 512 blocks = 2/CU for latency hiding).
// ---------------------------------------------------------------------------
__global__ __launch_bounds__(256) void outproj_kernel(
    const unsigned short* __restrict__ ao, const unsigned short* __restrict__ wt,
    const float* __restrict__ bo, float* __restrict__ out)
{
    __shared__ uint8_t smem[24576];
    const int t = threadIdx.x, l = t&63, w = t>>6, g = l>>4, ln = l&15;
    const unsigned short* WTz = wt + (size_t)3*(D_*D_);
    const int m0 = blockIdx.x*128, n0 = blockIdx.y*64;
    uint8_t* As = smem; uint8_t* Bs = smem + 16384;
    const int RB = (w>>1)*64, CB = (w&1)*32;

    const f32x4 zz = {0.f,0.f,0.f,0.f};
    f32x4 acc[4][2];
    #pragma unroll
    for (int i=0;i<4;i++)
        #pragma unroll
        for (int j=0;j<2;j++) acc[i][j] = zz;

    for (int k0=0; k0<D_; k0+=64){
        __syncthreads();
        // stage WT tile [64 n][64 k]: 8 chunks
        #pragma unroll
        for (int i=0;i<2;i++){
            int qc = w + i*4;
            int row = qc*8 + (l>>3);
            int colb = ((l&7)*16) ^ ((row&7)<<4);
            gload_lds16((const uint8_t*)WTz + (((size_t)(n0+row)*D_ + k0)<<1) + colb,
                        Bs + qc*1024);
        }
        // stage ao tile [128 m][64 k]: 16 chunks
        #pragma unroll
        for (int i=0;i<4;i++){
            int qc = w + i*4;
            int row = qc*8 + (l>>3);
            int colb = ((l&7)*16) ^ ((row&7)<<4);
            gload_lds16((const uint8_t*)ao + (((size_t)(m0+row)*D_ + k0)<<1) + colb,
                        As + qc*1024);
        }
        __syncthreads();
        #pragma unroll
        for (int kc=0; kc<2; kc++){
            short8 af[4], bfr[2];
            #pragma unroll
            for (int ai=0; ai<4; ai++){
                int row = RB + 16*ai + ln;
                af[ai] = *(const short8*)(As + row*128 + ((16*g + 64*kc) ^ ((row&7)<<4)));
            }
            #pragma unroll
            for (int bj=0; bj<2; bj++){
                int row = CB + 16*bj + ln;
                bfr[bj] = *(const short8*)(Bs + row*128 + ((16*g + 64*kc) ^ ((row&7)<<4)));
            }
            #pragma unroll
            for (int ai=0; ai<4; ai++)
                #pragma unroll
                for (int bj=0; bj<2; bj++)
                    acc[ai][bj] = MFMA16(af[ai], bfr[bj], acc[ai][bj]);
        }
    }

    #pragma unroll
    for (int bj=0; bj<2; bj++){
        int gn = n0 + CB + 16*bj + ln;
        float bv2 = bo[gn];
        #pragma unroll
        for (int ai=0; ai<4; ai++){
            #pragma unroll
            for (int r=0;r<4;r++){
                int gm = m0 + RB + 16*ai + 4*g + r;
                out[(size_t)gm*D_ + gn] = acc[ai][bj][r] + bv2;
            }
        }
    }
}

// ---------------------------------------------------------------------------
extern "C" void kernel_launch(void* const* d_in, const int* in_sizes, int n_in,
                              void* d_out, int out_size, void* d_ws, size_t ws_size,
                              hipStream_t stream)
{
    const float* q  = (const float*)d_in[0];
    const float* k  = (const float*)d_in[1];
    const float* v  = (const float*)d_in[2];
    const int* mask = (const int*)d_in[3];
    const float* wq = (const float*)d_in[4];
    const float* bq = (const float*)d_in[5];
    const float* wk = (const float*)d_in[6];
    const float* bk = (const float*)d_in[7];
    const float* wv = (const float*)d_in[8];
    const float* bv = (const float*)d_in[9];
    const float* wo = (const float*)d_in[10];
    const float* bo = (const float*)d_in[11];

    uint8_t* ws = (uint8_t*)d_ws;
    // ws layout (bytes):
    //   0        : qb bf16 [B][H][S][64]            (8388608)
    //   8388608  : kb bf16 [B][H][S][64]            (8388608)
    //   16777216 : vt bf16 [B][512][S] (pair-perm)  (8388608)
    //   25165824 : ao bf16 [8192][512]              (8388608)
    //   33554432 : WT bf16 [4][512][512]            (2097152)
    //   35651584 : mask bits u32 [B*S*64]           (2097152)
    unsigned short* qkvb = (unsigned short*)ws;
    unsigned short* ao   = (unsigned short*)(ws + 25165824);
    unsigned short* wt   = (unsigned short*)(ws + 33554432);
    uint32_t*       mb   = (uint32_t*)      (ws + 35651584);
    float* out = (float*)d_out;

    prep_kernel<<<dim3(4096), dim3(256), 0, stream>>>(wq, wk, wv, wo, wt);
    proj_kernel<<<dim3(64,4,11), dim3(256), 0, stream>>>(q, k, v, bq, bk, bv, wt, qkvb, mask, mb);
    attn_kernel<<<dim3(32,32), dim3(256), 0, stream>>>(qkvb, qkvb + 4194304, qkvb + 8388608, mb, ao);
    outproj_kernel<<<dim3(64,8), dim3(256), 0, stream>>>(ao, wt, bo, out);
}